// Round 4
// baseline (3600.472 us; speedup 1.0000x reference)
//
#include <hip/hip_runtime.h>

#define N_NODES 50000
#define E_EDGES 800000
#define DIMF    128

// ---------------------------------------------------------------------------
// Tiled fp32 GEMM: C[rows,128] = X[rows,128] @ W[128,128]
// block = 256 threads, 64 rows; blockIdx.y selects (Wq,Wk,Wv)->(Q,K,V).
// Thread (ty,tx): rows ty*4+r, cols tx*8+c  -> B reads & C stores are float4.
// ---------------------------------------------------------------------------
__global__ __launch_bounds__(256, 3) void node_proj3(const float* __restrict__ X,
                                                     const float* __restrict__ Wq,
                                                     const float* __restrict__ Wk,
                                                     const float* __restrict__ Wv,
                                                     float* __restrict__ Q,
                                                     float* __restrict__ K,
                                                     float* __restrict__ V,
                                                     int nrows) {
    const float* W = (blockIdx.y == 0) ? Wq : (blockIdx.y == 1) ? Wk : Wv;
    float*       C = (blockIdx.y == 0) ? Q  : (blockIdx.y == 1) ? K  : V;

    __shared__ float xs[64][132];
    __shared__ float wt[32][132];
    const int tid = threadIdx.x;
    const int row0 = blockIdx.x * 64;

    #pragma unroll
    for (int t = 0; t < 8; ++t) {
        int f4 = tid + t * 256;
        int r  = f4 >> 5;
        int c4 = f4 & 31;
        float4 v = make_float4(0.f, 0.f, 0.f, 0.f);
        if (row0 + r < nrows)
            v = *reinterpret_cast<const float4*>(X + (size_t)(row0 + r) * DIMF + c4 * 4);
        *reinterpret_cast<float4*>(&xs[r][c4 * 4]) = v;
    }

    const int ty = tid >> 4, tx = tid & 15;
    float acc[4][8];
    #pragma unroll
    for (int r = 0; r < 4; ++r)
        #pragma unroll
        for (int c = 0; c < 8; ++c) acc[r][c] = 0.f;

    for (int kc = 0; kc < 4; ++kc) {
        __syncthreads();
        #pragma unroll
        for (int t = 0; t < 4; ++t) {
            int f4 = tid + t * 256;
            int r  = f4 >> 5;
            int c4 = f4 & 31;
            *reinterpret_cast<float4*>(&wt[r][c4 * 4]) =
                *reinterpret_cast<const float4*>(W + (size_t)(kc * 32 + r) * DIMF + c4 * 4);
        }
        __syncthreads();
        #pragma unroll
        for (int d = 0; d < 32; ++d) {
            float a[4];
            #pragma unroll
            for (int r = 0; r < 4; ++r) a[r] = xs[ty * 4 + r][kc * 32 + d];
            float4 b0 = *reinterpret_cast<const float4*>(&wt[d][tx * 8]);
            float4 b1 = *reinterpret_cast<const float4*>(&wt[d][tx * 8 + 4]);
            #pragma unroll
            for (int r = 0; r < 4; ++r) {
                acc[r][0] = fmaf(a[r], b0.x, acc[r][0]);
                acc[r][1] = fmaf(a[r], b0.y, acc[r][1]);
                acc[r][2] = fmaf(a[r], b0.z, acc[r][2]);
                acc[r][3] = fmaf(a[r], b0.w, acc[r][3]);
                acc[r][4] = fmaf(a[r], b1.x, acc[r][4]);
                acc[r][5] = fmaf(a[r], b1.y, acc[r][5]);
                acc[r][6] = fmaf(a[r], b1.z, acc[r][6]);
                acc[r][7] = fmaf(a[r], b1.w, acc[r][7]);
            }
        }
    }

    #pragma unroll
    for (int r = 0; r < 4; ++r) {
        int grow = row0 + ty * 4 + r;
        if (grow < nrows) {
            *reinterpret_cast<float4*>(C + (size_t)grow * DIMF + tx * 8) =
                make_float4(acc[r][0], acc[r][1], acc[r][2], acc[r][3]);
            *reinterpret_cast<float4*>(C + (size_t)grow * DIMF + tx * 8 + 4) =
                make_float4(acc[r][4], acc[r][5], acc[r][6], acc[r][7]);
        }
    }
}

// ---------------------------------------------------------------------------
// Fused edge pass, two column-passes to halve acc registers + LDS:
//   P0: ek(64x128) = es @ Wek  -> logits (pair-shuffle dot) -> ex (4 regs)
//   P1: ev(64x128) = es @ Wev  (same acc regs) -> atomics
// Thread (ty,tx): edges ty*4+r, cols j = tx*8+c  (head/eh = tx>>1,
// d = (tx&1)*8+c). Per-head dot = local 8-fma + shfl_xor(1); head broadcast
// via 8x shfl(width=16). Occupancy target: LDS 49KB + VGPR<=168 -> 3 blk/CU.
// ---------------------------------------------------------------------------
__global__ __launch_bounds__(256, 3) void edge_pass(const float* __restrict__ Ed,
    const float* __restrict__ Wek, const float* __restrict__ Wev,
    const float* __restrict__ Wexp,
    const float* __restrict__ Q, const float* __restrict__ K,
    const float* __restrict__ V,
    const int* __restrict__ srcI, const int* __restrict__ dstI,
    float* __restrict__ agg, float* __restrict__ denom) {

    __shared__ float es[64][129];   // stride 129: a-reads land on 4 distinct banks
    __shared__ float wt[32][132];
    __shared__ float wexp_s[64];

    const int tid = threadIdx.x;
    const size_t e0 = (size_t)blockIdx.x * 64;

    if (tid < 64) wexp_s[tid] = Wexp[tid];

    // stage edge tile (64x128); E is an exact multiple of 64 -> no guard
    #pragma unroll
    for (int t = 0; t < 8; ++t) {
        int f4 = tid + t * 256;
        int r  = f4 >> 5;
        int c4 = f4 & 31;
        *reinterpret_cast<float4*>(&es[r][c4 * 4]) =
            *reinterpret_cast<const float4*>(Ed + (e0 + r) * DIMF + c4 * 4);
    }

    const int ty = tid >> 4, tx = tid & 15;
    const int eh = tx >> 1;

    int sidx[4], tidx[4];
    #pragma unroll
    for (int r = 0; r < 4; ++r) {
        sidx[r] = srcI[e0 + ty * 4 + r];
        tidx[r] = dstI[e0 + ty * 4 + r];
    }

    float acc[4][8];
    float ex[4];
    const float scale = 0.25f;  // HD^-0.5

    // ================= PASS 0: ek + logits + exp =================
    #pragma unroll
    for (int r = 0; r < 4; ++r)
        #pragma unroll
        for (int c = 0; c < 8; ++c) acc[r][c] = 0.f;

    for (int kc = 0; kc < 4; ++kc) {
        __syncthreads();   // also covers es/wexp_s staging on kc==0, wt reuse later
        #pragma unroll
        for (int t = 0; t < 4; ++t) {
            int f4 = tid + t * 256;
            int r  = f4 >> 5;
            int c4 = f4 & 31;
            *reinterpret_cast<float4*>(&wt[r][c4 * 4]) =
                *reinterpret_cast<const float4*>(Wek + (size_t)(kc * 32 + r) * DIMF + c4 * 4);
        }
        __syncthreads();
        #pragma unroll
        for (int d = 0; d < 32; ++d) {
            float a[4];
            #pragma unroll
            for (int r = 0; r < 4; ++r) a[r] = es[ty * 4 + r][kc * 32 + d];
            float4 b0 = *reinterpret_cast<const float4*>(&wt[d][tx * 8]);
            float4 b1 = *reinterpret_cast<const float4*>(&wt[d][tx * 8 + 4]);
            #pragma unroll
            for (int r = 0; r < 4; ++r) {
                acc[r][0] = fmaf(a[r], b0.x, acc[r][0]);
                acc[r][1] = fmaf(a[r], b0.y, acc[r][1]);
                acc[r][2] = fmaf(a[r], b0.z, acc[r][2]);
                acc[r][3] = fmaf(a[r], b0.w, acc[r][3]);
                acc[r][4] = fmaf(a[r], b1.x, acc[r][4]);
                acc[r][5] = fmaf(a[r], b1.y, acc[r][5]);
                acc[r][6] = fmaf(a[r], b1.z, acc[r][6]);
                acc[r][7] = fmaf(a[r], b1.w, acc[r][7]);
            }
        }
    }

    #pragma unroll
    for (int r = 0; r < 4; ++r) {
        const size_t qb = (size_t)sidx[r] * DIMF + tx * 8;
        const size_t kb = (size_t)tidx[r] * DIMF + tx * 8;
        float4 q0 = *reinterpret_cast<const float4*>(Q + qb);
        float4 q1 = *reinterpret_cast<const float4*>(Q + qb + 4);
        float4 k0 = *reinterpret_cast<const float4*>(K + kb);
        float4 k1 = *reinterpret_cast<const float4*>(K + kb + 4);
        float p = 0.f;
        p = fmaf(q0.x, k0.x + acc[r][0], p);
        p = fmaf(q0.y, k0.y + acc[r][1], p);
        p = fmaf(q0.z, k0.z + acc[r][2], p);
        p = fmaf(q0.w, k0.w + acc[r][3], p);
        p = fmaf(q1.x, k1.x + acc[r][4], p);
        p = fmaf(q1.y, k1.y + acc[r][5], p);
        p = fmaf(q1.z, k1.z + acc[r][6], p);
        p = fmaf(q1.w, k1.w + acc[r][7], p);
        p *= scale;
        p += __shfl_xor(p, 1);          // pair -> full 16-d head dot
        float aeh = 0.f;
        #pragma unroll
        for (int h = 0; h < 8; ++h) {
            float ph = __shfl(p, h * 2, 16);   // head h lives in lane-pair 2h of 16-group
            aeh = fmaf(ph, wexp_s[h * 8 + eh], aeh);
        }
        ex[r] = __expf(aeh);
        if ((tx & 1) == 0)
            atomicAdd(&denom[(size_t)sidx[r] * 8 + eh], ex[r]);
    }

    // ================= PASS 1: ev + scatter =================
    #pragma unroll
    for (int r = 0; r < 4; ++r)
        #pragma unroll
        for (int c = 0; c < 8; ++c) acc[r][c] = 0.f;

    for (int kc = 0; kc < 4; ++kc) {
        __syncthreads();   // all waves done reading previous wt
        #pragma unroll
        for (int t = 0; t < 4; ++t) {
            int f4 = tid + t * 256;
            int r  = f4 >> 5;
            int c4 = f4 & 31;
            *reinterpret_cast<float4*>(&wt[r][c4 * 4]) =
                *reinterpret_cast<const float4*>(Wev + (size_t)(kc * 32 + r) * DIMF + c4 * 4);
        }
        __syncthreads();
        #pragma unroll
        for (int d = 0; d < 32; ++d) {
            float a[4];
            #pragma unroll
            for (int r = 0; r < 4; ++r) a[r] = es[ty * 4 + r][kc * 32 + d];
            float4 b0 = *reinterpret_cast<const float4*>(&wt[d][tx * 8]);
            float4 b1 = *reinterpret_cast<const float4*>(&wt[d][tx * 8 + 4]);
            #pragma unroll
            for (int r = 0; r < 4; ++r) {
                acc[r][0] = fmaf(a[r], b0.x, acc[r][0]);
                acc[r][1] = fmaf(a[r], b0.y, acc[r][1]);
                acc[r][2] = fmaf(a[r], b0.z, acc[r][2]);
                acc[r][3] = fmaf(a[r], b0.w, acc[r][3]);
                acc[r][4] = fmaf(a[r], b1.x, acc[r][4]);
                acc[r][5] = fmaf(a[r], b1.y, acc[r][5]);
                acc[r][6] = fmaf(a[r], b1.z, acc[r][6]);
                acc[r][7] = fmaf(a[r], b1.w, acc[r][7]);
            }
        }
    }

    #pragma unroll
    for (int r = 0; r < 4; ++r) {
        const size_t vb = (size_t)tidx[r] * DIMF + tx * 8;
        float4 v0 = *reinterpret_cast<const float4*>(V + vb);
        float4 v1 = *reinterpret_cast<const float4*>(V + vb + 4);
        float* ap = agg + (size_t)sidx[r] * DIMF + tx * 8;
        atomicAdd(ap + 0, ex[r] * (v0.x + acc[r][0]));
        atomicAdd(ap + 1, ex[r] * (v0.y + acc[r][1]));
        atomicAdd(ap + 2, ex[r] * (v0.z + acc[r][2]));
        atomicAdd(ap + 3, ex[r] * (v0.w + acc[r][3]));
        atomicAdd(ap + 4, ex[r] * (v1.x + acc[r][4]));
        atomicAdd(ap + 5, ex[r] * (v1.y + acc[r][5]));
        atomicAdd(ap + 6, ex[r] * (v1.z + acc[r][6]));
        atomicAdd(ap + 7, ex[r] * (v1.w + acc[r][7]));
    }
}

// ---------------------------------------------------------------------------
// finalize: out = (V - agg/denom) @ W_out   (denom==0 -> pre = V)
// ---------------------------------------------------------------------------
__global__ __launch_bounds__(256, 3) void finalize(const float* __restrict__ V,
    const float* __restrict__ agg, const float* __restrict__ denom,
    const float* __restrict__ Wout, float* __restrict__ out, int nrows) {
    __shared__ float xs[64][132];
    __shared__ float wt[32][132];
    const int tid = threadIdx.x;
    const int row0 = blockIdx.x * 64;

    #pragma unroll
    for (int t = 0; t < 8; ++t) {
        int f4 = tid + t * 256;
        int r  = f4 >> 5;
        int c4 = f4 & 31;
        float4 v = make_float4(0.f, 0.f, 0.f, 0.f);
        if (row0 + r < nrows) {
            size_t base = (size_t)(row0 + r) * DIMF + c4 * 4;
            float4 vv = *reinterpret_cast<const float4*>(V + base);
            float4 ag = *reinterpret_cast<const float4*>(agg + base);
            float den = denom[(size_t)(row0 + r) * 8 + c4 / 4];  // eh = (c4*4)/16
            float inv = den > 0.f ? 1.f / den : 0.f;
            v.x = vv.x - ag.x * inv;
            v.y = vv.y - ag.y * inv;
            v.z = vv.z - ag.z * inv;
            v.w = vv.w - ag.w * inv;
        }
        *reinterpret_cast<float4*>(&xs[r][c4 * 4]) = v;
    }

    const int ty = tid >> 4, tx = tid & 15;
    float acc[4][8];
    #pragma unroll
    for (int r = 0; r < 4; ++r)
        #pragma unroll
        for (int c = 0; c < 8; ++c) acc[r][c] = 0.f;

    for (int kc = 0; kc < 4; ++kc) {
        __syncthreads();
        #pragma unroll
        for (int t = 0; t < 4; ++t) {
            int f4 = tid + t * 256;
            int r  = f4 >> 5;
            int c4 = f4 & 31;
            *reinterpret_cast<float4*>(&wt[r][c4 * 4]) =
                *reinterpret_cast<const float4*>(Wout + (size_t)(kc * 32 + r) * DIMF + c4 * 4);
        }
        __syncthreads();
        #pragma unroll
        for (int d = 0; d < 32; ++d) {
            float a[4];
            #pragma unroll
            for (int r = 0; r < 4; ++r) a[r] = xs[ty * 4 + r][kc * 32 + d];
            float4 b0 = *reinterpret_cast<const float4*>(&wt[d][tx * 8]);
            float4 b1 = *reinterpret_cast<const float4*>(&wt[d][tx * 8 + 4]);
            #pragma unroll
            for (int r = 0; r < 4; ++r) {
                acc[r][0] = fmaf(a[r], b0.x, acc[r][0]);
                acc[r][1] = fmaf(a[r], b0.y, acc[r][1]);
                acc[r][2] = fmaf(a[r], b0.z, acc[r][2]);
                acc[r][3] = fmaf(a[r], b0.w, acc[r][3]);
                acc[r][4] = fmaf(a[r], b1.x, acc[r][4]);
                acc[r][5] = fmaf(a[r], b1.y, acc[r][5]);
                acc[r][6] = fmaf(a[r], b1.z, acc[r][6]);
                acc[r][7] = fmaf(a[r], b1.w, acc[r][7]);
            }
        }
    }

    #pragma unroll
    for (int r = 0; r < 4; ++r) {
        int grow = row0 + ty * 4 + r;
        if (grow < nrows) {
            *reinterpret_cast<float4*>(out + (size_t)grow * DIMF + tx * 8) =
                make_float4(acc[r][0], acc[r][1], acc[r][2], acc[r][3]);
            *reinterpret_cast<float4*>(out + (size_t)grow * DIMF + tx * 8 + 4) =
                make_float4(acc[r][4], acc[r][5], acc[r][6], acc[r][7]);
        }
    }
}

// ---------------------------------------------------------------------------
extern "C" void kernel_launch(void* const* d_in, const int* in_sizes, int n_in,
                              void* d_out, int out_size, void* d_ws, size_t ws_size,
                              hipStream_t stream) {
    const float* x     = (const float*)d_in[0];
    const float* edges = (const float*)d_in[1];
    const float* Wq    = (const float*)d_in[2];
    const float* Wk    = (const float*)d_in[3];
    const float* Wv    = (const float*)d_in[4];
    const float* Wek   = (const float*)d_in[5];
    const float* Wev   = (const float*)d_in[6];
    const float* Wexp  = (const float*)d_in[7];
    const float* Wout  = (const float*)d_in[8];
    const int*   eidx  = (const int*)d_in[9];
    const int*   srcI  = eidx;             // edge_index[0]
    const int*   dstI  = eidx + E_EDGES;   // edge_index[1]
    float* out = (float*)d_out;

    float* Q     = (float*)d_ws;                    // N*128
    float* Kp    = Q     + (size_t)N_NODES * DIMF;  // N*128
    float* Vn    = Kp    + (size_t)N_NODES * DIMF;  // N*128
    float* agg   = Vn    + (size_t)N_NODES * DIMF;  // N*128
    float* denom = agg   + (size_t)N_NODES * DIMF;  // N*8

    // zero agg + denom (contiguous; capture-safe async memset)
    hipMemsetAsync(agg, 0, ((size_t)N_NODES * DIMF + (size_t)N_NODES * 8) * sizeof(float), stream);

    const int nb = (N_NODES + 63) / 64;
    dim3 grid3(nb, 3);
    node_proj3<<<grid3, 256, 0, stream>>>(x, Wq, Wk, Wv, Q, Kp, Vn, N_NODES);

    edge_pass<<<E_EDGES / 64, 256, 0, stream>>>(edges, Wek, Wev, Wexp,
                                                Q, Kp, Vn, srcI, dstI, agg, denom);

    finalize<<<nb, 256, 0, stream>>>(Vn, agg, denom, Wout, out, N_NODES);
}

// Round 7
// 1666.474 us; speedup vs baseline: 2.1605x; 2.1605x over previous
//
#include <hip/hip_runtime.h>

#define N_NODES 50000
#define E_EDGES 800000
#define DIMF    128

// ---------------------------------------------------------------------------
// Tiled fp32 GEMM: C[rows,128] = X[rows,128] @ W[128,128]
// block = 256 threads, 64 rows; blockIdx.y selects (Wq,Wk,Wv)->(Q,K,V).
// Thread (ty,tx): rows ty*4+r, cols tx+16*c. Scalar wt reads are
// conflict-free (16 consecutive banks x 4-way same-address broadcast,
// measured 0 conflicts in R3); float4 reads were 4-way conflicted (R4).
// ---------------------------------------------------------------------------
__global__ __launch_bounds__(256, 3) void node_proj3(const float* __restrict__ X,
                                                     const float* __restrict__ Wq,
                                                     const float* __restrict__ Wk,
                                                     const float* __restrict__ Wv,
                                                     float* __restrict__ Q,
                                                     float* __restrict__ K,
                                                     float* __restrict__ V,
                                                     int nrows) {
    const float* W = (blockIdx.y == 0) ? Wq : (blockIdx.y == 1) ? Wk : Wv;
    float*       C = (blockIdx.y == 0) ? Q  : (blockIdx.y == 1) ? K  : V;

    __shared__ float xs[64][132];
    __shared__ float wt[32][132];
    const int tid = threadIdx.x;
    const int row0 = blockIdx.x * 64;

    #pragma unroll
    for (int t = 0; t < 8; ++t) {
        int f4 = tid + t * 256;
        int r  = f4 >> 5;
        int c4 = f4 & 31;
        float4 v = make_float4(0.f, 0.f, 0.f, 0.f);
        if (row0 + r < nrows)
            v = *reinterpret_cast<const float4*>(X + (size_t)(row0 + r) * DIMF + c4 * 4);
        *reinterpret_cast<float4*>(&xs[r][c4 * 4]) = v;
    }

    const int ty = tid >> 4, tx = tid & 15;
    float acc[4][8];
    #pragma unroll
    for (int r = 0; r < 4; ++r)
        #pragma unroll
        for (int c = 0; c < 8; ++c) acc[r][c] = 0.f;

    for (int kc = 0; kc < 4; ++kc) {
        __syncthreads();
        #pragma unroll
        for (int t = 0; t < 4; ++t) {
            int f4 = tid + t * 256;
            int r  = f4 >> 5;
            int c4 = f4 & 31;
            *reinterpret_cast<float4*>(&wt[r][c4 * 4]) =
                *reinterpret_cast<const float4*>(W + (size_t)(kc * 32 + r) * DIMF + c4 * 4);
        }
        __syncthreads();
        #pragma unroll
        for (int d = 0; d < 32; ++d) {
            float a[4], b[8];
            #pragma unroll
            for (int r = 0; r < 4; ++r) a[r] = xs[ty * 4 + r][kc * 32 + d];
            #pragma unroll
            for (int c = 0; c < 8; ++c) b[c] = wt[d][tx + 16 * c];
            #pragma unroll
            for (int r = 0; r < 4; ++r)
                #pragma unroll
                for (int c = 0; c < 8; ++c) acc[r][c] = fmaf(a[r], b[c], acc[r][c]);
        }
    }

    #pragma unroll
    for (int r = 0; r < 4; ++r) {
        int grow = row0 + ty * 4 + r;
        if (grow < nrows) {
            #pragma unroll
            for (int c = 0; c < 8; ++c)
                C[(size_t)grow * DIMF + tx + 16 * c] = acc[r][c];
        }
    }
}

// ---------------------------------------------------------------------------
// Fused edge pass, two column-passes (keeps R4's occupancy win: acc 32 VGPR,
// LDS ~50KB, 3 blocks/CU) with R3's conflict-free tx+16c column mapping
// (keeps 0 LDS bank conflicts + 64B-contiguous-per-instruction atomics).
//   P0: ek(64x128) = es @ Wek -> logits (shfl_xor reduce) -> ex[4][8]
//   P1: ev(64x128) = es @ Wev (same acc regs) -> atomics
// Thread (ty,tx): edges ty*4+r, cols tx+16c (P0: head c, d=tx; P1: eh c, d=tx).
// ---------------------------------------------------------------------------
__global__ __launch_bounds__(256, 3) void edge_pass(const float* __restrict__ Ed,
    const float* __restrict__ Wek, const float* __restrict__ Wev,
    const float* __restrict__ Wexp,
    const float* __restrict__ Q, const float* __restrict__ K,
    const float* __restrict__ V,
    const int* __restrict__ srcI, const int* __restrict__ dstI,
    float* __restrict__ agg, float* __restrict__ denom) {

    __shared__ float es[64][129];   // a-reads: 4 distinct banks, 16-lane broadcast
    __shared__ float wt[32][132];
    __shared__ float wexp_s[64];

    const int tid = threadIdx.x;
    const size_t e0 = (size_t)blockIdx.x * 64;

    if (tid < 64) wexp_s[tid] = Wexp[tid];

    // stage edge tile (64x128); E is an exact multiple of 64 -> no guard
    #pragma unroll
    for (int t = 0; t < 8; ++t) {
        int f4 = tid + t * 256;
        int r  = f4 >> 5;
        int c4 = f4 & 31;
        *reinterpret_cast<float4*>(&es[r][c4 * 4]) =
            *reinterpret_cast<const float4*>(Ed + (e0 + r) * DIMF + c4 * 4);
    }

    const int ty = tid >> 4, tx = tid & 15;

    int sidx[4], tidx[4];
    #pragma unroll
    for (int r = 0; r < 4; ++r) {
        sidx[r] = srcI[e0 + ty * 4 + r];
        tidx[r] = dstI[e0 + ty * 4 + r];
    }

    float acc[4][8];
    float ex[4][8];
    const float scale = 0.25f;  // HD^-0.5

    // ================= PASS 0: ek + logits + exp =================
    #pragma unroll
    for (int r = 0; r < 4; ++r)
        #pragma unroll
        for (int c = 0; c < 8; ++c) acc[r][c] = 0.f;

    for (int kc = 0; kc < 4; ++kc) {
        __syncthreads();   // waves done reading previous wt (also orders es/wexp staging)
        #pragma unroll
        for (int t = 0; t < 4; ++t) {
            int f4 = tid + t * 256;
            int r  = f4 >> 5;
            int c4 = f4 & 31;
            *reinterpret_cast<float4*>(&wt[r][c4 * 4]) =
                *reinterpret_cast<const float4*>(Wek + (size_t)(kc * 32 + r) * DIMF + c4 * 4);
        }
        __syncthreads();
        #pragma unroll
        for (int d = 0; d < 32; ++d) {
            float a[4], b[8];
            #pragma unroll
            for (int r = 0; r < 4; ++r) a[r] = es[ty * 4 + r][kc * 32 + d];
            #pragma unroll
            for (int c = 0; c < 8; ++c) b[c] = wt[d][tx + 16 * c];
            #pragma unroll
            for (int r = 0; r < 4; ++r)
                #pragma unroll
                for (int c = 0; c < 8; ++c) acc[r][c] = fmaf(a[r], b[c], acc[r][c]);
        }
    }

    #pragma unroll
    for (int r = 0; r < 4; ++r) {
        const int s = sidx[r];
        const int t = tidx[r];
        // per-head partial dot: this lane holds d=tx for all 8 heads
        float p[8];
        #pragma unroll
        for (int c = 0; c < 8; ++c) {
            float qv = Q[(size_t)s * DIMF + c * 16 + tx];
            float kv = K[(size_t)t * DIMF + c * 16 + tx];
            p[c] = qv * (kv + acc[r][c]) * scale;
        }
        // reduce over the 16-lane d-group -> p[h] uniform in group
        #pragma unroll
        for (int off = 1; off < 16; off <<= 1) {
            #pragma unroll
            for (int c = 0; c < 8; ++c) p[c] += __shfl_xor(p[c], off, 64);
        }
        // expand heads: a[eh] = sum_h p[h]*Wexp[h,eh]; ex = exp(a)
        // (no max subtraction: logits ~ N(0,0.064^2), overflow impossible)
        float dsum = 0.f;
        #pragma unroll
        for (int c2 = 0; c2 < 8; ++c2) {
            float a = 0.f;
            #pragma unroll
            for (int h = 0; h < 8; ++h) a = fmaf(p[h], wexp_s[h * 8 + c2], a);
            ex[r][c2] = __expf(a);
            dsum = (tx == c2) ? ex[r][c2] : dsum;   // static-index select (rule #20)
        }
        if (tx < 8) atomicAdd(&denom[(size_t)s * 8 + tx], dsum);
    }

    // ================= PASS 1: ev + scatter =================
    #pragma unroll
    for (int r = 0; r < 4; ++r)
        #pragma unroll
        for (int c = 0; c < 8; ++c) acc[r][c] = 0.f;

    for (int kc = 0; kc < 4; ++kc) {
        __syncthreads();   // all waves done reading previous wt
        #pragma unroll
        for (int t = 0; t < 4; ++t) {
            int f4 = tid + t * 256;
            int r  = f4 >> 5;
            int c4 = f4 & 31;
            *reinterpret_cast<float4*>(&wt[r][c4 * 4]) =
                *reinterpret_cast<const float4*>(Wev + (size_t)(kc * 32 + r) * DIMF + c4 * 4);
        }
        __syncthreads();
        #pragma unroll
        for (int d = 0; d < 32; ++d) {
            float a[4], b[8];
            #pragma unroll
            for (int r = 0; r < 4; ++r) a[r] = es[ty * 4 + r][kc * 32 + d];
            #pragma unroll
            for (int c = 0; c < 8; ++c) b[c] = wt[d][tx + 16 * c];
            #pragma unroll
            for (int r = 0; r < 4; ++r)
                #pragma unroll
                for (int c = 0; c < 8; ++c) acc[r][c] = fmaf(a[r], b[c], acc[r][c]);
        }
    }

    // scatter: per (r,c2) instruction the 16 lanes cover 64 contiguous bytes
    #pragma unroll
    for (int r = 0; r < 4; ++r) {
        const int s = sidx[r];
        const int t = tidx[r];
        #pragma unroll
        for (int c2 = 0; c2 < 8; ++c2) {
            float vv = V[(size_t)t * DIMF + c2 * 16 + tx];
            atomicAdd(&agg[(size_t)s * DIMF + c2 * 16 + tx],
                      ex[r][c2] * (vv + acc[r][c2]));
        }
    }
}

// ---------------------------------------------------------------------------
// finalize: out = (V - agg/denom) @ W_out   (denom==0 -> pre = V)
// ---------------------------------------------------------------------------
__global__ __launch_bounds__(256, 3) void finalize(const float* __restrict__ V,
    const float* __restrict__ agg, const float* __restrict__ denom,
    const float* __restrict__ Wout, float* __restrict__ out, int nrows) {
    __shared__ float xs[64][132];
    __shared__ float wt[32][132];
    const int tid = threadIdx.x;
    const int row0 = blockIdx.x * 64;

    #pragma unroll
    for (int t = 0; t < 8; ++t) {
        int f4 = tid + t * 256;
        int r  = f4 >> 5;
        int c4 = f4 & 31;
        float4 v = make_float4(0.f, 0.f, 0.f, 0.f);
        if (row0 + r < nrows) {
            size_t base = (size_t)(row0 + r) * DIMF + c4 * 4;
            float4 vv = *reinterpret_cast<const float4*>(V + base);
            float4 ag = *reinterpret_cast<const float4*>(agg + base);
            float den = denom[(size_t)(row0 + r) * 8 + c4 / 4];  // eh = (c4*4)/16
            float inv = den > 0.f ? 1.f / den : 0.f;
            v.x = vv.x - ag.x * inv;
            v.y = vv.y - ag.y * inv;
            v.z = vv.z - ag.z * inv;
            v.w = vv.w - ag.w * inv;
        }
        *reinterpret_cast<float4*>(&xs[r][c4 * 4]) = v;
    }

    const int ty = tid >> 4, tx = tid & 15;
    float acc[4][8];
    #pragma unroll
    for (int r = 0; r < 4; ++r)
        #pragma unroll
        for (int c = 0; c < 8; ++c) acc[r][c] = 0.f;

    for (int kc = 0; kc < 4; ++kc) {
        __syncthreads();
        #pragma unroll
        for (int t = 0; t < 4; ++t) {
            int f4 = tid + t * 256;
            int r  = f4 >> 5;
            int c4 = f4 & 31;
            *reinterpret_cast<float4*>(&wt[r][c4 * 4]) =
                *reinterpret_cast<const float4*>(Wout + (size_t)(kc * 32 + r) * DIMF + c4 * 4);
        }
        __syncthreads();
        #pragma unroll
        for (int d = 0; d < 32; ++d) {
            float a[4], b[8];
            #pragma unroll
            for (int r = 0; r < 4; ++r) a[r] = xs[ty * 4 + r][kc * 32 + d];
            #pragma unroll
            for (int c = 0; c < 8; ++c) b[c] = wt[d][tx + 16 * c];
            #pragma unroll
            for (int r = 0; r < 4; ++r)
                #pragma unroll
                for (int c = 0; c < 8; ++c) acc[r][c] = fmaf(a[r], b[c], acc[r][c]);
        }
    }

    #pragma unroll
    for (int r = 0; r < 4; ++r) {
        int grow = row0 + ty * 4 + r;
        if (grow < nrows) {
            #pragma unroll
            for (int c = 0; c < 8; ++c)
                out[(size_t)grow * DIMF + tx + 16 * c] = acc[r][c];
        }
    }
}

// ---------------------------------------------------------------------------
extern "C" void kernel_launch(void* const* d_in, const int* in_sizes, int n_in,
                              void* d_out, int out_size, void* d_ws, size_t ws_size,
                              hipStream_t stream) {
    const float* x     = (const float*)d_in[0];
    const float* edges = (const float*)d_in[1];
    const float* Wq    = (const float*)d_in[2];
    const float* Wk    = (const float*)d_in[3];
    const float* Wv    = (const float*)d_in[4];
    const float* Wek   = (const float*)d_in[5];
    const float* Wev   = (const float*)d_in[6];
    const float* Wexp  = (const float*)d_in[7];
    const float* Wout  = (const float*)d_in[8];
    const int*   eidx  = (const int*)d_in[9];
    const int*   srcI  = eidx;             // edge_index[0]
    const int*   dstI  = eidx + E_EDGES;   // edge_index[1]
    float* out = (float*)d_out;

    float* Q     = (float*)d_ws;                    // N*128
    float* Kp    = Q     + (size_t)N_NODES * DIMF;  // N*128
    float* Vn    = Kp    + (size_t)N_NODES * DIMF;  // N*128
    float* agg   = Vn    + (size_t)N_NODES * DIMF;  // N*128
    float* denom = agg   + (size_t)N_NODES * DIMF;  // N*8

    // zero agg + denom (contiguous; capture-safe async memset)
    hipMemsetAsync(agg, 0, ((size_t)N_NODES * DIMF + (size_t)N_NODES * 8) * sizeof(float), stream);

    const int nb = (N_NODES + 63) / 64;
    dim3 grid3(nb, 3);
    node_proj3<<<grid3, 256, 0, stream>>>(x, Wq, Wk, Wv, Q, Kp, Vn, N_NODES);

    edge_pass<<<E_EDGES / 64, 256, 0, stream>>>(edges, Wek, Wev, Wexp,
                                                Q, Kp, Vn, srcI, dstI, agg, denom);

    finalize<<<nb, 256, 0, stream>>>(Vn, agg, denom, Wout, out, N_NODES);
}

// Round 8
// 1303.505 us; speedup vs baseline: 2.7621x; 1.2785x over previous
//
#include <hip/hip_runtime.h>
#include <hip/hip_bf16.h>

#define N_NODES 50000
#define E_EDGES 800000
#define DIMF    128

typedef __attribute__((ext_vector_type(8))) short short8v;   // 8 bf16 (4 VGPR) MFMA A/B frag
typedef __attribute__((ext_vector_type(4))) float f32x4;     // MFMA C/D frag

static __device__ __forceinline__ short f2bf(float f) {
    __hip_bfloat16 h = __float2bfloat16(f);
    return *reinterpret_cast<short*>(&h);
}
static __device__ __forceinline__ float bf2f(short s) {
    __hip_bfloat16 h = *reinterpret_cast<__hip_bfloat16*>(&s);
    return __bfloat162float(h);
}

// ---------------------------------------------------------------------------
// Pre-pack W = [Wek | Wev] (128x256 fp32) into hi/lo bf16 fragment order.
// Frag slot convention (MUST match edge_pass A-side): element j of lane l at
// k-step ks, col-tile ct holds W[k][n], k = ks*32 + (l>>4)*8 + j,
// n = ct*16 + (l&15).  Flat index = ((ct*4+ks)*64 + l)*8 + j.
// Same bijection on A and B => correct product for any HW slot order.
// ---------------------------------------------------------------------------
__global__ __launch_bounds__(256) void wsplit(const float* __restrict__ Wek,
                                              const float* __restrict__ Wev,
                                              short* __restrict__ Whi,
                                              short* __restrict__ Wlo) {
    int idx = blockIdx.x * 256 + threadIdx.x;     // 0..32767
    int j  = idx & 7;
    int l  = (idx >> 3) & 63;
    int ks = (idx >> 9) & 3;
    int ct = idx >> 11;                           // 0..15
    int k = ks * 32 + (l >> 4) * 8 + j;
    int n = ct * 16 + (l & 15);
    float f = (n < 128) ? Wek[k * 128 + n] : Wev[k * 128 + (n - 128)];
    short hi = f2bf(f);
    Whi[idx] = hi;
    Wlo[idx] = f2bf(f - bf2f(hi));                // exact residual (>=8-bit exp gap)
}

// ---------------------------------------------------------------------------
// Tiled fp32 GEMM: C[rows,128] = X[rows,128] @ W[128,128]  (unchanged, R3-good)
// ---------------------------------------------------------------------------
__global__ __launch_bounds__(256, 3) void node_proj3(const float* __restrict__ X,
                                                     const float* __restrict__ Wq,
                                                     const float* __restrict__ Wk,
                                                     const float* __restrict__ Wv,
                                                     float* __restrict__ Q,
                                                     float* __restrict__ K,
                                                     float* __restrict__ V,
                                                     int nrows) {
    const float* W = (blockIdx.y == 0) ? Wq : (blockIdx.y == 1) ? Wk : Wv;
    float*       C = (blockIdx.y == 0) ? Q  : (blockIdx.y == 1) ? K  : V;

    __shared__ float xs[64][132];
    __shared__ float wt[32][132];
    const int tid = threadIdx.x;
    const int row0 = blockIdx.x * 64;

    #pragma unroll
    for (int t = 0; t < 8; ++t) {
        int f4 = tid + t * 256;
        int r  = f4 >> 5;
        int c4 = f4 & 31;
        float4 v = make_float4(0.f, 0.f, 0.f, 0.f);
        if (row0 + r < nrows)
            v = *reinterpret_cast<const float4*>(X + (size_t)(row0 + r) * DIMF + c4 * 4);
        *reinterpret_cast<float4*>(&xs[r][c4 * 4]) = v;
    }

    const int ty = tid >> 4, tx = tid & 15;
    float acc[4][8];
    #pragma unroll
    for (int r = 0; r < 4; ++r)
        #pragma unroll
        for (int c = 0; c < 8; ++c) acc[r][c] = 0.f;

    for (int kc = 0; kc < 4; ++kc) {
        __syncthreads();
        #pragma unroll
        for (int t = 0; t < 4; ++t) {
            int f4 = tid + t * 256;
            int r  = f4 >> 5;
            int c4 = f4 & 31;
            *reinterpret_cast<float4*>(&wt[r][c4 * 4]) =
                *reinterpret_cast<const float4*>(W + (size_t)(kc * 32 + r) * DIMF + c4 * 4);
        }
        __syncthreads();
        #pragma unroll
        for (int d = 0; d < 32; ++d) {
            float a[4], b[8];
            #pragma unroll
            for (int r = 0; r < 4; ++r) a[r] = xs[ty * 4 + r][kc * 32 + d];
            #pragma unroll
            for (int c = 0; c < 8; ++c) b[c] = wt[d][tx + 16 * c];
            #pragma unroll
            for (int r = 0; r < 4; ++r)
                #pragma unroll
                for (int c = 0; c < 8; ++c) acc[r][c] = fmaf(a[r], b[c], acc[r][c]);
        }
    }

    #pragma unroll
    for (int r = 0; r < 4; ++r) {
        int grow = row0 + ty * 4 + r;
        if (grow < nrows) {
            #pragma unroll
            for (int c = 0; c < 8; ++c)
                C[(size_t)grow * DIMF + tx + 16 * c] = acc[r][c];
        }
    }
}

// ---------------------------------------------------------------------------
// MFMA fused edge pass. Per block: 64 edges.
//   [ek|ev](64x256) = es(64x128) @ W(128x256) via 16x16x32 bf16 MFMA,
//   hi/lo split: acc += Ahi*Bhi + Alo*Bhi + Ahi*Blo   (error ~2^-17 rel).
// Wave w owns M-tile w (16 edges) x all 16 N-tiles; acc[16] f32x4.
// C layout (m89-verified): col = lane&15, row-in-tile = (lane>>4)*4 + reg.
// Epilogue identical in memory pattern to R7 (0-conflict gathers, 64B atomics):
//   logits via 16-lane shfl reduce -> W_exp -> exp (overflow-safe, no max)
//   -> denom atomic (32B burst) -> agg atomics (8x 64B-contiguous per edge).
// Single __syncthreads per block (es staging only); B frags stream from
// L2-resident pre-packed Whi/Wlo (no LDS, no per-kstep barriers).
// ---------------------------------------------------------------------------
__global__ __launch_bounds__(256, 3) void edge_pass(const float* __restrict__ Ed,
    const short* __restrict__ Whi, const short* __restrict__ Wlo,
    const float* __restrict__ Wexp,
    const float* __restrict__ Q, const float* __restrict__ K,
    const float* __restrict__ V,
    const int* __restrict__ srcI, const int* __restrict__ dstI,
    float* __restrict__ agg, float* __restrict__ denom) {

    __shared__ short es_hi[64][136];   // +8 bf16 pad: row stride 272B (16B-aligned)
    __shared__ short es_lo[64][136];
    __shared__ float wexp_s[64];

    const int tid = threadIdx.x;
    const size_t e0 = (size_t)blockIdx.x * 64;

    if (tid < 64) wexp_s[tid] = Wexp[tid];

    // stage edge tile (64x128 fp32) -> hi/lo bf16 in LDS. E % 64 == 0.
    #pragma unroll
    for (int t = 0; t < 8; ++t) {
        int f4 = tid + t * 256;
        int r  = f4 >> 5;
        int c4 = f4 & 31;
        float4 v = *reinterpret_cast<const float4*>(Ed + (e0 + r) * DIMF + c4 * 4);
        short4 hi, lo;
        hi.x = f2bf(v.x); lo.x = f2bf(v.x - bf2f(hi.x));
        hi.y = f2bf(v.y); lo.y = f2bf(v.y - bf2f(hi.y));
        hi.z = f2bf(v.z); lo.z = f2bf(v.z - bf2f(hi.z));
        hi.w = f2bf(v.w); lo.w = f2bf(v.w - bf2f(hi.w));
        *reinterpret_cast<short4*>(&es_hi[r][c4 * 4]) = hi;
        *reinterpret_cast<short4*>(&es_lo[r][c4 * 4]) = lo;
    }
    __syncthreads();

    const int w  = tid >> 6;     // wave 0..3 -> M-tile (edges w*16..w*16+15)
    const int l  = tid & 63;
    const int lg = l >> 4;       // k-group / C row-group
    const int lm = l & 15;       // A row / C col

    f32x4 acc[16];
    #pragma unroll
    for (int nt = 0; nt < 16; ++nt) {
        f32x4 z = {0.f, 0.f, 0.f, 0.f};
        acc[nt] = z;
    }

    const int arow = w * 16 + lm;
    #pragma unroll
    for (int ks = 0; ks < 4; ++ks) {
        short8v ahi = *reinterpret_cast<const short8v*>(&es_hi[arow][ks * 32 + lg * 8]);
        short8v alo = *reinterpret_cast<const short8v*>(&es_lo[arow][ks * 32 + lg * 8]);
        #pragma unroll
        for (int nt = 0; nt < 16; ++nt) {
            const size_t fb = ((size_t)(nt * 4 + ks) * 64 + l) * 8;
            short8v bhi = *reinterpret_cast<const short8v*>(Whi + fb);
            short8v blo = *reinterpret_cast<const short8v*>(Wlo + fb);
            acc[nt] = __builtin_amdgcn_mfma_f32_16x16x32_bf16(ahi, bhi, acc[nt], 0, 0, 0);
            acc[nt] = __builtin_amdgcn_mfma_f32_16x16x32_bf16(alo, bhi, acc[nt], 0, 0, 0);
            acc[nt] = __builtin_amdgcn_mfma_f32_16x16x32_bf16(ahi, blo, acc[nt], 0, 0, 0);
        }
    }

    // ---- epilogue: this thread covers edges w*16 + lg*4 + j (j=0..3), d=lm ----
    int sidx[4], tidx[4];
    #pragma unroll
    for (int j = 0; j < 4; ++j) {
        size_t eg = e0 + w * 16 + lg * 4 + j;
        sidx[j] = srcI[eg];
        tidx[j] = dstI[eg];
    }

    const float scale = 0.25f;   // HD^-0.5
    float ex[4][8];
    #pragma unroll
    for (int j = 0; j < 4; ++j) {
        const int s = sidx[j];
        const int t = tidx[j];
        float p[8];
        #pragma unroll
        for (int h = 0; h < 8; ++h) {
            float qv = Q[(size_t)s * DIMF + h * 16 + lm];
            float kv = K[(size_t)t * DIMF + h * 16 + lm];
            p[h] = qv * (kv + acc[h][j]) * scale;   // acc[h] reg j = C[edge j][h*16+lm]
        }
        #pragma unroll
        for (int off = 1; off < 16; off <<= 1) {
            #pragma unroll
            for (int h = 0; h < 8; ++h) p[h] += __shfl_xor(p[h], off, 64);
        }
        // a[eh] = sum_h p[h]*Wexp[h,eh]; ex = exp(a). No max: logits ~N(0,0.064^2).
        float dsum = 0.f;
        #pragma unroll
        for (int c2 = 0; c2 < 8; ++c2) {
            float a = 0.f;
            #pragma unroll
            for (int h = 0; h < 8; ++h) a = fmaf(p[h], wexp_s[h * 8 + c2], a);
            ex[j][c2] = __expf(a);
            dsum = (lm == c2) ? ex[j][c2] : dsum;   // static-index select (rule #20)
        }
        if (lm < 8) atomicAdd(&denom[(size_t)s * 8 + lm], dsum);
    }

    #pragma unroll
    for (int j = 0; j < 4; ++j) {
        const int s = sidx[j];
        const int t = tidx[j];
        #pragma unroll
        for (int c2 = 0; c2 < 8; ++c2) {
            float vv = V[(size_t)t * DIMF + c2 * 16 + lm];
            atomicAdd(&agg[(size_t)s * DIMF + c2 * 16 + lm],
                      ex[j][c2] * (vv + acc[8 + c2][j]));
        }
    }
}

// ---------------------------------------------------------------------------
// finalize: out = (V - agg/denom) @ W_out   (denom==0 -> pre = V)  (unchanged)
// ---------------------------------------------------------------------------
__global__ __launch_bounds__(256, 3) void finalize(const float* __restrict__ V,
    const float* __restrict__ agg, const float* __restrict__ denom,
    const float* __restrict__ Wout, float* __restrict__ out, int nrows) {
    __shared__ float xs[64][132];
    __shared__ float wt[32][132];
    const int tid = threadIdx.x;
    const int row0 = blockIdx.x * 64;

    #pragma unroll
    for (int t = 0; t < 8; ++t) {
        int f4 = tid + t * 256;
        int r  = f4 >> 5;
        int c4 = f4 & 31;
        float4 v = make_float4(0.f, 0.f, 0.f, 0.f);
        if (row0 + r < nrows) {
            size_t base = (size_t)(row0 + r) * DIMF + c4 * 4;
            float4 vv = *reinterpret_cast<const float4*>(V + base);
            float4 ag = *reinterpret_cast<const float4*>(agg + base);
            float den = denom[(size_t)(row0 + r) * 8 + c4 / 4];  // eh = (c4*4)/16
            float inv = den > 0.f ? 1.f / den : 0.f;
            v.x = vv.x - ag.x * inv;
            v.y = vv.y - ag.y * inv;
            v.z = vv.z - ag.z * inv;
            v.w = vv.w - ag.w * inv;
        }
        *reinterpret_cast<float4*>(&xs[r][c4 * 4]) = v;
    }

    const int ty = tid >> 4, tx = tid & 15;
    float acc[4][8];
    #pragma unroll
    for (int r = 0; r < 4; ++r)
        #pragma unroll
        for (int c = 0; c < 8; ++c) acc[r][c] = 0.f;

    for (int kc = 0; kc < 4; ++kc) {
        __syncthreads();
        #pragma unroll
        for (int t = 0; t < 4; ++t) {
            int f4 = tid + t * 256;
            int r  = f4 >> 5;
            int c4 = f4 & 31;
            *reinterpret_cast<float4*>(&wt[r][c4 * 4]) =
                *reinterpret_cast<const float4*>(Wout + (size_t)(kc * 32 + r) * DIMF + c4 * 4);
        }
        __syncthreads();
        #pragma unroll
        for (int d = 0; d < 32; ++d) {
            float a[4], b[8];
            #pragma unroll
            for (int r = 0; r < 4; ++r) a[r] = xs[ty * 4 + r][kc * 32 + d];
            #pragma unroll
            for (int c = 0; c < 8; ++c) b[c] = wt[d][tx + 16 * c];
            #pragma unroll
            for (int r = 0; r < 4; ++r)
                #pragma unroll
                for (int c = 0; c < 8; ++c) acc[r][c] = fmaf(a[r], b[c], acc[r][c]);
        }
    }

    #pragma unroll
    for (int r = 0; r < 4; ++r) {
        int grow = row0 + ty * 4 + r;
        if (grow < nrows) {
            #pragma unroll
            for (int c = 0; c < 8; ++c)
                out[(size_t)grow * DIMF + tx + 16 * c] = acc[r][c];
        }
    }
}

// ---------------------------------------------------------------------------
extern "C" void kernel_launch(void* const* d_in, const int* in_sizes, int n_in,
                              void* d_out, int out_size, void* d_ws, size_t ws_size,
                              hipStream_t stream) {
    const float* x     = (const float*)d_in[0];
    const float* edges = (const float*)d_in[1];
    const float* Wq    = (const float*)d_in[2];
    const float* Wk    = (const float*)d_in[3];
    const float* Wv    = (const float*)d_in[4];
    const float* Wek   = (const float*)d_in[5];
    const float* Wev   = (const float*)d_in[6];
    const float* Wexp  = (const float*)d_in[7];
    const float* Wout  = (const float*)d_in[8];
    const int*   eidx  = (const int*)d_in[9];
    const int*   srcI  = eidx;             // edge_index[0]
    const int*   dstI  = eidx + E_EDGES;   // edge_index[1]
    float* out = (float*)d_out;

    float* Q     = (float*)d_ws;                    // N*128
    float* Kp    = Q     + (size_t)N_NODES * DIMF;  // N*128
    float* Vn    = Kp    + (size_t)N_NODES * DIMF;  // N*128
    float* agg   = Vn    + (size_t)N_NODES * DIMF;  // N*128
    float* denom = agg   + (size_t)N_NODES * DIMF;  // N*8
    short* Whi   = (short*)(denom + (size_t)N_NODES * 8);  // 32768 bf16 (16B-aligned)
    short* Wlo   = Whi + 32768;

    // zero agg + denom (contiguous; capture-safe async memset)
    hipMemsetAsync(agg, 0, ((size_t)N_NODES * DIMF + (size_t)N_NODES * 8) * sizeof(float), stream);

    wsplit<<<128, 256, 0, stream>>>(Wek, Wev, Whi, Wlo);

    const int nb = (N_NODES + 63) / 64;
    dim3 grid3(nb, 3);
    node_proj3<<<grid3, 256, 0, stream>>>(x, Wq, Wk, Wv, Q, Kp, Vn, N_NODES);

    edge_pass<<<E_EDGES / 64, 256, 0, stream>>>(edges, Whi, Wlo, Wexp,
                                                Q, Kp, Vn, srcI, dstI, agg, denom);

    finalize<<<nb, 256, 0, stream>>>(Vn, agg, denom, Wout, out, N_NODES);
}